// Round 14
// baseline (844.669 us; speedup 1.0000x reference)
//
#include <hip/hip_runtime.h>
#include <hip/hip_bf16.h>
#include <cstdint>

// Problem constants (from reference)
#define TT     2048   // tokens
#define KSEL   6      // experts per token
#define DMODEL 2048   // model dim
#define DINTER 1408   // moe intermediate dim
#define NE     16     // routed experts
#define PMAX   (TT * KSEL)

typedef short bf16x8 __attribute__((ext_vector_type(8)));
typedef float f32x4 __attribute__((ext_vector_type(4)));
typedef unsigned short u16;
typedef u16 u16x8 __attribute__((ext_vector_type(8)));

__device__ __forceinline__ u16 f2bf(float f) {
  union { float f; unsigned u; } v; v.f = f;
  return (u16)((v.u + 0x7FFFu + ((v.u >> 16) & 1u)) >> 16);  // RNE
}

// fp32->bf16 via HIP cast (compiler emits packed cvt; RNE)
__device__ __forceinline__ u16 f2bfh(float f) {
  __hip_bfloat16 h = __float2bfloat16(f);
  u16 r; __builtin_memcpy(&r, &h, 2); return r;
}

__device__ __forceinline__ void gl2lds16(const void* g, void* l) {
  __builtin_amdgcn_global_load_lds((const __attribute__((address_space(1))) void*)g,
                                   (__attribute__((address_space(3))) void*)l,
                                   16, 0, 0);
}

#define BAR_RAW() asm volatile("s_barrier" ::: "memory")
// full drain BEFORE issuing next-tile B loads (order-robust; see R9 NaN lesson):
// B(kb) already consumed via register dep, B(kb+1) not yet issued, so this only
// drains the A gl2lds + commits ds_writes.
#define DRAIN() asm volatile("s_waitcnt vmcnt(0) lgkmcnt(0)" ::: "memory")

// gate_w[t,e] = sum_k weights[t,k]*(indices[t,k]==e); count routed (t,e) pairs
__global__ void k_gate(const float* __restrict__ w, const int* __restrict__ idx,
                       float* __restrict__ gate_w, int* __restrict__ counts) {
  int g = blockIdx.x * 256 + threadIdx.x;  // T*E threads
  int t = g >> 4, e = g & 15;
  const int* ip = idx + t * KSEL;
  const float* wp = w + t * KSEL;
  float s = 0.f;
#pragma unroll
  for (int k = 0; k < KSEL; ++k) s += (ip[k] == e) ? wp[k] : 0.f;
  gate_w[g] = s;
  if (s != 0.f) atomicAdd(counts + e, 1);
}

__global__ void k_scan(const int* __restrict__ counts, int* __restrict__ offs) {
  if (threadIdx.x == 0 && blockIdx.x == 0) {
    int r = 0;
#pragma unroll
    for (int e = 0; e < NE; ++e) { offs[e] = r; r += counts[e]; }
    offs[NE] = r;
  }
}

__global__ void k_fill(const float* __restrict__ gate_w, const int* __restrict__ offs,
                       int* __restrict__ cursor, int* __restrict__ slot_tok,
                       float* __restrict__ slot_gate) {
  int g = blockIdx.x * 256 + threadIdx.x;
  int t = g >> 4, e = g & 15;
  float s = gate_w[g];
  if (s != 0.f) {
    int p = atomicAdd(cursor + e, 1);
    int sl = offs[e] + p;
    slot_tok[sl] = t;
    slot_gate[sl] = s;
  }
}

// fp32 -> bf16 cast for x only (16 MB)
__global__ void k_castx(const float* __restrict__ x, u16* __restrict__ xb) {
  int i = blockIdx.x * 256 + threadIdx.x;  // 8 elems per thread
  const float4* p = (const float4*)x + (size_t)i * 2;
  float4 v0 = p[0], v1 = p[1];
  u16x8 o;
  o[0] = f2bf(v0.x); o[1] = f2bf(v0.y); o[2] = f2bf(v0.z); o[3] = f2bf(v0.w);
  o[4] = f2bf(v1.x); o[5] = f2bf(v1.y); o[6] = f2bf(v1.z); o[7] = f2bf(v1.w);
  *(u16x8*)(xb + (size_t)i * 8) = o;
}

// ---------------------------------------------------------------------------
// GEMM1 with FUSED weight cast (R12 core + XCD-chunked swizzle restored).
// R12's 1.11 GB FETCH was the MISSING swizzle: linear order spread the 16
// mt-blocks of one (it,e) fp32 panel across 8 non-coherent L2s. With the R6
// decode, the 2 MB panel is L2-resident -> weights fetched ~once from HBM.
// B (Wg,Wu): fp32 global->reg->bf16->swizzled ds_write; next-tile B loads
// issued after DRAIN so they fly across the barrier+MFMA phase (T14).
// A (xb): global_load_lds. LDS row 64 bf16 = 8 units; XOR u' = u ^ (row&7)
// on write AND read (rule #21).
// ---------------------------------------------------------------------------
__global__ __launch_bounds__(256, 2) void k_gemm1(
    const u16* __restrict__ xb, const float* __restrict__ Wg, const float* __restrict__ Wu,
    const int* __restrict__ slot_tok, const float* __restrict__ slot_gate,
    const int* __restrict__ offs, const int* __restrict__ counts,
    u16* __restrict__ act) {
  // XCD-chunked swizzle: grid flat = 16(mt) x 11(it) x 16(e) = 2816 = 8*352
  int b = blockIdx.x;
  int w = (b & 7) * 352 + (b >> 3);
  int mt = w & 15, rest = w >> 4;
  int it = rest % 11, e = rest / 11;

  int mcount = counts[e];
  if (mt * 128 >= mcount) return;
  int mrem = mcount - mt * 128; if (mrem > 128) mrem = 128;
  int slotBase = offs[e] + mt * 128;
  int iBase = it * 128;

  __shared__ u16 sA[128 * 64];
  __shared__ u16 sG[128 * 64];
  __shared__ u16 sU[128 * 64];
  __shared__ int tokLds[128];
  __shared__ float gateLds[128];

  int tid = threadIdx.x;
  if (tid < 128) {
    int rl = tid < mrem ? tid : 0;
    tokLds[tid] = slot_tok[slotBase + rl];
    gateLds[tid] = (tid < mrem) ? slot_gate[slotBase + rl] : 0.f;
  }
  __syncthreads();

  int wv = tid >> 6, lane = tid & 63;
  // A staging: 16 chunks of 1KB; linear LDS dest, source unit pre-swizzled
  const u16* aSrc[4]; u16* aDst[4];
  int r8 = lane >> 3;
  int colOff = ((lane & 7) ^ r8) * 8;
#pragma unroll
  for (int i2 = 0; i2 < 4; ++i2) {
    int chunk = wv * 4 + i2;
    int row = chunk * 8 + r8;
    aSrc[i2] = xb + (size_t)tokLds[row] * DMODEL + colOff;
    aDst[i2] = sA + chunk * 512;
  }

  // B fp32 staging: 128 rows x 64 cols fp32 per tensor per K-step.
  int srow = tid >> 1, sc0 = (tid & 1) * 32;
  const float* gS = Wg + ((size_t)e * DINTER + iBase + srow) * DMODEL + sc0;
  const float* uS = Wu + ((size_t)e * DINTER + iBase + srow) * DMODEL + sc0;
  int wrBase = srow * 64;
  int u4 = (tid & 1) * 4;

  f32x4 vg[8], vu[8];
  auto LOADB = [&](int kk) {
#pragma unroll
    for (int j = 0; j < 8; ++j) {
      vg[j] = *(const f32x4*)(gS + kk * 64 + j * 4);
      vu[j] = *(const f32x4*)(uS + kk * 64 + j * 4);
    }
  };

  f32x4 accg[4][4] = {};
  f32x4 accu[4][4] = {};
  int fr = lane & 15, fq = lane >> 4;
  int wr = (wv >> 1) * 64, wc = (wv & 1) * 64;

  LOADB(0);   // prologue: tile-0 B loads in flight

#pragma unroll 1
  for (int kb = 0; kb < DMODEL / 64; ++kb) {
    BAR_RAW();                         // all waves done reading prev LDS tile
#pragma unroll
    for (int i2 = 0; i2 < 4; ++i2) gl2lds16(aSrc[i2] + kb * 64, aDst[i2]);
    // convert B(kb) (register dep auto-waits its loads) + swizzled ds_write
#pragma unroll
    for (int w2 = 0; w2 < 4; ++w2) {
      union { u16 h[8]; bf16x8 v; } og, ou;
#pragma unroll
      for (int q = 0; q < 8; ++q) {
        og.h[q] = f2bfh(vg[w2 * 2 + (q >> 2)][q & 3]);
        ou.h[q] = f2bfh(vu[w2 * 2 + (q >> 2)][q & 3]);
      }
      int du = (((u4 + w2) ^ (srow & 7)) << 3);
      *(bf16x8*)&sG[wrBase + du] = og.v;
      *(bf16x8*)&sU[wrBase + du] = ou.v;
    }
    DRAIN();                           // A landed + ds_writes committed
    LOADB((kb + 1) & 31);              // next-tile B: in flight across barrier
    BAR_RAW();
#pragma unroll
    for (int kf = 0; kf < 2; ++kf) {
      bf16x8 af[4], bg[4], bu[4];
#pragma unroll
      for (int mf = 0; mf < 4; ++mf) {
        int row = wr + mf * 16 + fr;
        int cu = ((kf * 4 + fq) ^ (row & 7)) * 8;
        af[mf] = *(const bf16x8*)&sA[row * 64 + cu];
      }
#pragma unroll
      for (int nf = 0; nf < 4; ++nf) {
        int row = wc + nf * 16 + fr;
        int cu = ((kf * 4 + fq) ^ (row & 7)) * 8;
        bg[nf] = *(const bf16x8*)&sG[row * 64 + cu];
        bu[nf] = *(const bf16x8*)&sU[row * 64 + cu];
      }
#pragma unroll
      for (int mf = 0; mf < 4; ++mf)
#pragma unroll
        for (int nf = 0; nf < 4; ++nf) {
          accg[mf][nf] = __builtin_amdgcn_mfma_f32_16x16x32_bf16(af[mf], bg[nf], accg[mf][nf], 0, 0, 0);
          accu[mf][nf] = __builtin_amdgcn_mfma_f32_16x16x32_bf16(af[mf], bu[nf], accu[mf][nf], 0, 0, 0);
        }
    }
  }
  // epilogue: act = silu(g)*u*gate -> bf16  (D layout: col=lane&15, row=(lane>>4)*4+r)
#pragma unroll
  for (int mf = 0; mf < 4; ++mf)
#pragma unroll
    for (int nf = 0; nf < 4; ++nf)
#pragma unroll
      for (int r = 0; r < 4; ++r) {
        int row = wr + mf * 16 + fq * 4 + r;
        if (row < mrem) {
          float g = accg[mf][nf][r], u = accu[mf][nf][r];
          float a = g / (1.f + __expf(-g)) * u * gateLds[row];
          act[(size_t)(slotBase + row) * DINTER + iBase + wc + nf * 16 + fr] = f2bf(a);
        }
      }
}

// GEMM2 with fused Wd cast (R12 core + XCD swizzle): A = act via
// global_load_lds; B = Wd fp32 reg-staged. y scatter via atomicAdd.
__global__ __launch_bounds__(256, 3) void k_gemm2(
    const u16* __restrict__ act, const float* __restrict__ Wd,
    const int* __restrict__ slot_tok, const int* __restrict__ offs,
    const int* __restrict__ counts, float* __restrict__ y) {
  // XCD-chunked: grid flat = 16(mt) x 16(dt) x 16(e) = 4096 = 8*512
  int b = blockIdx.x;
  int w = (b & 7) * 512 + (b >> 3);
  int mt = w & 15, rest = w >> 4;
  int dt = rest & 15, e = rest >> 4;

  int mcount = counts[e];
  if (mt * 128 >= mcount) return;
  int mrem = mcount - mt * 128; if (mrem > 128) mrem = 128;
  int slotBase = offs[e] + mt * 128;
  int dBase = dt * 128;

  __shared__ u16 sA[128 * 64];
  __shared__ u16 sB[128 * 64];
  __shared__ int tokLds[128];

  int tid = threadIdx.x;
  if (tid < 128) tokLds[tid] = slot_tok[slotBase + (tid < mrem ? tid : 0)];
  __syncthreads();

  int wv = tid >> 6, lane = tid & 63;
  const u16* aSrc[4]; u16* aDst[4];
  int r8 = lane >> 3;
  int colOff = ((lane & 7) ^ r8) * 8;
#pragma unroll
  for (int i2 = 0; i2 < 4; ++i2) {
    int chunk = wv * 4 + i2;
    int row = chunk * 8 + r8;
    aSrc[i2] = act + (size_t)(slotBase + row) * DINTER + colOff;  // act padded rows
    aDst[i2] = sA + chunk * 512;
  }

  int srow = tid >> 1, sc0 = (tid & 1) * 32;
  const float* bS = Wd + ((size_t)e * DMODEL + dBase + srow) * DINTER + sc0;
  int wrBase = srow * 64;
  int u4 = (tid & 1) * 4;

  f32x4 vb[8];
  auto LOADB = [&](int kk) {
#pragma unroll
    for (int j = 0; j < 8; ++j) vb[j] = *(const f32x4*)(bS + kk * 64 + j * 4);
  };

  f32x4 acc[4][4] = {};
  int fr = lane & 15, fq = lane >> 4;
  int wr = (wv >> 1) * 64, wc = (wv & 1) * 64;

  const int NT = DINTER / 64;  // 22
  LOADB(0);

#pragma unroll 1
  for (int kb = 0; kb < NT; ++kb) {
    BAR_RAW();
#pragma unroll
    for (int i2 = 0; i2 < 4; ++i2) gl2lds16(aSrc[i2] + kb * 64, aDst[i2]);
#pragma unroll
    for (int w2 = 0; w2 < 4; ++w2) {
      union { u16 h[8]; bf16x8 v; } ob;
#pragma unroll
      for (int q = 0; q < 8; ++q) ob.h[q] = f2bfh(vb[w2 * 2 + (q >> 2)][q & 3]);
      int du = (((u4 + w2) ^ (srow & 7)) << 3);
      *(bf16x8*)&sB[wrBase + du] = ob.v;
    }
    DRAIN();
    LOADB((kb + 1 == NT) ? 0 : kb + 1);
    BAR_RAW();
#pragma unroll
    for (int kf = 0; kf < 2; ++kf) {
      bf16x8 af[4], bb[4];
#pragma unroll
      for (int mf = 0; mf < 4; ++mf) {
        int row = wr + mf * 16 + fr;
        int cu = ((kf * 4 + fq) ^ (row & 7)) * 8;
        af[mf] = *(const bf16x8*)&sA[row * 64 + cu];
      }
#pragma unroll
      for (int nf = 0; nf < 4; ++nf) {
        int row = wc + nf * 16 + fr;
        int cu = ((kf * 4 + fq) ^ (row & 7)) * 8;
        bb[nf] = *(const bf16x8*)&sB[row * 64 + cu];
      }
#pragma unroll
      for (int mf = 0; mf < 4; ++mf)
#pragma unroll
        for (int nf = 0; nf < 4; ++nf)
          acc[mf][nf] = __builtin_amdgcn_mfma_f32_16x16x32_bf16(af[mf], bb[nf], acc[mf][nf], 0, 0, 0);
    }
  }
#pragma unroll
  for (int mf = 0; mf < 4; ++mf)
#pragma unroll
    for (int nf = 0; nf < 4; ++nf)
#pragma unroll
      for (int r = 0; r < 4; ++r) {
        int row = wr + mf * 16 + fq * 4 + r;
        if (row < mrem) {
          int t = tokLds[row];
          atomicAdd(y + (size_t)t * DMODEL + dBase + wc + nf * 16 + fr, acc[mf][nf][r]);
        }
      }
}

extern "C" void kernel_launch(void* const* d_in, const int* in_sizes, int n_in,
                              void* d_out, int out_size, void* d_ws, size_t ws_size,
                              hipStream_t stream) {
  const float* x       = (const float*)d_in[0];
  const float* weights = (const float*)d_in[1];
  const int*   indices = (const int*)d_in[2];
  const float* Wg      = (const float*)d_in[3];
  const float* Wu      = (const float*)d_in[4];
  const float* Wd      = (const float*)d_in[5];
  float* y = (float*)d_out;

  char* ws = (char*)d_ws;
  size_t o = 0;
  float* gate_w = (float*)(ws + o); o += (size_t)TT * NE * 4;
  size_t ctrlOff = o;
  int* counts = (int*)(ws + o);
  int* offs   = (int*)(ws + o + 64);
  int* cursor = (int*)(ws + o + 192);
  o += 256;
  int*   slot_tok  = (int*)(ws + o);   o += (size_t)PMAX * 4;
  float* slot_gate = (float*)(ws + o); o += (size_t)PMAX * 4;
  u16* xb  = (u16*)(ws + o); o += (size_t)TT * DMODEL * 2;
  u16* act = (u16*)(ws + o); o += (size_t)(PMAX + 256) * DINTER * 2; // pad rows
  (void)ws_size; (void)in_sizes; (void)n_in;

  hipMemsetAsync(d_out, 0, (size_t)out_size * 4, stream);
  hipMemsetAsync(ws + ctrlOff, 0, 256, stream);

  k_gate<<<TT * NE / 256, 256, 0, stream>>>(weights, indices, gate_w, counts);
  k_scan<<<1, 64, 0, stream>>>(counts, offs);
  k_fill<<<TT * NE / 256, 256, 0, stream>>>(gate_w, offs, cursor, slot_tok, slot_gate);
  k_castx<<<(TT * DMODEL / 8) / 256, 256, 0, stream>>>(x, xb);
  k_gemm1<<<2816, 256, 0, stream>>>(xb, Wg, Wu, slot_tok, slot_gate, offs, counts, act);
  k_gemm2<<<4096, 256, 0, stream>>>(act, Wd, slot_tok, offs, counts, y);
}

// Round 15
// 807.400 us; speedup vs baseline: 1.0462x; 1.0462x over previous
//
#include <hip/hip_runtime.h>
#include <hip/hip_bf16.h>
#include <cstdint>

// Problem constants (from reference)
#define TT     2048   // tokens
#define KSEL   6      // experts per token
#define DMODEL 2048   // model dim
#define DINTER 1408   // moe intermediate dim
#define NE     16     // routed experts
#define PMAX   (TT * KSEL)

typedef short bf16x8 __attribute__((ext_vector_type(8)));
typedef float f32x4 __attribute__((ext_vector_type(4)));
typedef unsigned short u16;
typedef u16 u16x8 __attribute__((ext_vector_type(8)));

__device__ __forceinline__ u16 f2bf(float f) {
  union { float f; unsigned u; } v; v.f = f;
  return (u16)((v.u + 0x7FFFu + ((v.u >> 16) & 1u)) >> 16);  // RNE
}

__device__ __forceinline__ void gl2lds16(const void* g, void* l) {
  __builtin_amdgcn_global_load_lds((const __attribute__((address_space(1))) void*)g,
                                   (__attribute__((address_space(3))) void*)l,
                                   16, 0, 0);
}

// gate_w[t,e] = sum_k weights[t,k]*(indices[t,k]==e); count routed (t,e) pairs
__global__ void k_gate(const float* __restrict__ w, const int* __restrict__ idx,
                       float* __restrict__ gate_w, int* __restrict__ counts) {
  int g = blockIdx.x * 256 + threadIdx.x;  // T*E threads
  int t = g >> 4, e = g & 15;
  const int* ip = idx + t * KSEL;
  const float* wp = w + t * KSEL;
  float s = 0.f;
#pragma unroll
  for (int k = 0; k < KSEL; ++k) s += (ip[k] == e) ? wp[k] : 0.f;
  gate_w[g] = s;
  if (s != 0.f) atomicAdd(counts + e, 1);
}

__global__ void k_scan(const int* __restrict__ counts, int* __restrict__ offs) {
  if (threadIdx.x == 0 && blockIdx.x == 0) {
    int r = 0;
#pragma unroll
    for (int e = 0; e < NE; ++e) { offs[e] = r; r += counts[e]; }
    offs[NE] = r;
  }
}

__global__ void k_fill(const float* __restrict__ gate_w, const int* __restrict__ offs,
                       int* __restrict__ cursor, int* __restrict__ slot_tok,
                       float* __restrict__ slot_gate) {
  int g = blockIdx.x * 256 + threadIdx.x;
  int t = g >> 4, e = g & 15;
  float s = gate_w[g];
  if (s != 0.f) {
    int p = atomicAdd(cursor + e, 1);
    int sl = offs[e] + p;
    slot_tok[sl] = t;
    slot_gate[sl] = s;
  }
}

// single merged fp32->bf16 cast over 4 tensors (x, Wg, Wu, Wd), 8 elems/thread
// 1.27 GB total traffic -> ~200 us at BW floor (measured ~6 TB/s); optimal.
#define XV8   (TT * DMODEL / 8)                      // 524288
#define WV8   (NE * DINTER * DMODEL / 8)             // 5767168
__global__ void k_castall(const float* __restrict__ x,  u16* __restrict__ xb,
                          const float* __restrict__ wg, u16* __restrict__ wgb,
                          const float* __restrict__ wu, u16* __restrict__ wub,
                          const float* __restrict__ wd, u16* __restrict__ wdb) {
  const int total = XV8 + 3 * WV8;
  int stride = gridDim.x * 256;
  for (int i = blockIdx.x * 256 + threadIdx.x; i < total; i += stride) {
    const float* src; u16* dst; int j;
    if (i < XV8)                { src = x;  dst = xb;  j = i; }
    else if (i < XV8 + WV8)     { src = wg; dst = wgb; j = i - XV8; }
    else if (i < XV8 + 2 * WV8) { src = wu; dst = wub; j = i - XV8 - WV8; }
    else                        { src = wd; dst = wdb; j = i - XV8 - 2 * WV8; }
    const float4* p = (const float4*)src + (size_t)j * 2;
    float4 v0 = p[0], v1 = p[1];
    u16x8 o;
    o[0] = f2bf(v0.x); o[1] = f2bf(v0.y); o[2] = f2bf(v0.z); o[3] = f2bf(v0.w);
    o[4] = f2bf(v1.x); o[5] = f2bf(v1.y); o[6] = f2bf(v1.z); o[7] = f2bf(v1.w);
    *(u16x8*)(dst + (size_t)j * 8) = o;
  }
}

// ---------------------------------------------------------------------------
// LDS XOR swizzle (G4 / rule #21): rows are 64 bf16 = 8 16B-units; write side
// pre-permutes the GLOBAL source unit (u' = u ^ (row&7), LDS dest linear per
// gl2lds HW rule), read side applies the same XOR -> bank-conflict-free
// (R6 measured: SQ_LDS_BANK_CONFLICT = 0).
// ---------------------------------------------------------------------------

// GEMM1: act[slot, i] = silu(x@WgT)*(x@WuT)*gate, per expert token-group.
// R6 core; (256,3) -> 3 blocks/CU (150 KB LDS fits): more TLP hides the
// 2-phase barrier drain (m114 mechanism).
__global__ __launch_bounds__(256, 3) void k_gemm1(
    const u16* __restrict__ xb, const u16* __restrict__ wgb, const u16* __restrict__ wub,
    const int* __restrict__ slot_tok, const float* __restrict__ slot_gate,
    const int* __restrict__ offs, const int* __restrict__ counts,
    u16* __restrict__ act) {
  // XCD-chunked swizzle: grid flat = 16(mt) x 11(it) x 16(e) = 2816 = 8*352
  int b = blockIdx.x;
  int w = (b & 7) * 352 + (b >> 3);
  int mt = w & 15, rest = w >> 4;
  int it = rest % 11, e = rest / 11;

  int mcount = counts[e];
  if (mt * 128 >= mcount) return;
  int mrem = mcount - mt * 128; if (mrem > 128) mrem = 128;
  int slotBase = offs[e] + mt * 128;
  int iBase = it * 128;

  __shared__ u16 sA[128 * 64];
  __shared__ u16 sG[128 * 64];
  __shared__ u16 sU[128 * 64];
  __shared__ int tokLds[128];
  __shared__ float gateLds[128];

  int tid = threadIdx.x;
  if (tid < 128) {
    int rl = tid < mrem ? tid : 0;        // pad rows clamp to row 0 (valid addr)
    tokLds[tid] = slot_tok[slotBase + rl];
    gateLds[tid] = (tid < mrem) ? slot_gate[slotBase + rl] : 0.f;
  }
  __syncthreads();

  int wv = tid >> 6, lane = tid & 63;
  // staging: 16 chunks of 1KB (8 rows x 128B); linear LDS dest, swizzled source
  const u16 *aSrc[4], *gSrc[4], *uSrc[4];
  u16 *aDst[4], *gDst[4], *uDst[4];
  const u16* gBase = wgb + ((size_t)e * DINTER + iBase) * DMODEL;
  const u16* uBase = wub + ((size_t)e * DINTER + iBase) * DMODEL;
  int r8 = lane >> 3;
  int colOff = ((lane & 7) ^ r8) * 8;   // swizzled 16B-unit within the row
#pragma unroll
  for (int i2 = 0; i2 < 4; ++i2) {
    int chunk = wv * 4 + i2;
    int row = chunk * 8 + r8;
    aSrc[i2] = xb + (size_t)tokLds[row] * DMODEL + colOff;
    gSrc[i2] = gBase + (size_t)row * DMODEL + colOff;
    uSrc[i2] = uBase + (size_t)row * DMODEL + colOff;
    aDst[i2] = sA + chunk * 512;
    gDst[i2] = sG + chunk * 512;
    uDst[i2] = sU + chunk * 512;
  }

  f32x4 accg[4][4] = {};
  f32x4 accu[4][4] = {};
  int fr = lane & 15, fq = lane >> 4;
  int wr = (wv >> 1) * 64, wc = (wv & 1) * 64;

  for (int kb = 0; kb < DMODEL / 64; ++kb) {
    int kOff = kb * 64;
    __syncthreads();
#pragma unroll
    for (int i2 = 0; i2 < 4; ++i2) {
      gl2lds16(aSrc[i2] + kOff, aDst[i2]);
      gl2lds16(gSrc[i2] + kOff, gDst[i2]);
      gl2lds16(uSrc[i2] + kOff, uDst[i2]);
    }
    __syncthreads();
#pragma unroll
    for (int kf = 0; kf < 2; ++kf) {
      bf16x8 af[4], bg[4], bu[4];
#pragma unroll
      for (int mf = 0; mf < 4; ++mf) {
        int row = wr + mf * 16 + fr;
        int cu = ((kf * 4 + fq) ^ (row & 7)) * 8;
        af[mf] = *(const bf16x8*)&sA[row * 64 + cu];
      }
#pragma unroll
      for (int nf = 0; nf < 4; ++nf) {
        int row = wc + nf * 16 + fr;
        int cu = ((kf * 4 + fq) ^ (row & 7)) * 8;
        bg[nf] = *(const bf16x8*)&sG[row * 64 + cu];
        bu[nf] = *(const bf16x8*)&sU[row * 64 + cu];
      }
#pragma unroll
      for (int mf = 0; mf < 4; ++mf)
#pragma unroll
        for (int nf = 0; nf < 4; ++nf) {
          accg[mf][nf] = __builtin_amdgcn_mfma_f32_16x16x32_bf16(af[mf], bg[nf], accg[mf][nf], 0, 0, 0);
          accu[mf][nf] = __builtin_amdgcn_mfma_f32_16x16x32_bf16(af[mf], bu[nf], accu[mf][nf], 0, 0, 0);
        }
    }
  }
  // epilogue: act = silu(g)*u*gate -> bf16  (D layout: col=lane&15, row=(lane>>4)*4+r)
#pragma unroll
  for (int mf = 0; mf < 4; ++mf)
#pragma unroll
    for (int nf = 0; nf < 4; ++nf)
#pragma unroll
      for (int r = 0; r < 4; ++r) {
        int row = wr + mf * 16 + fq * 4 + r;
        if (row < mrem) {
          float g = accg[mf][nf][r], u = accu[mf][nf][r];
          float a = g / (1.f + __expf(-g)) * u * gateLds[row];
          act[(size_t)(slotBase + row) * DINTER + iBase + wc + nf * 16 + fr] = f2bf(a);
        }
      }
}

// GEMM2: y[tok, d] += act[slot,:] @ Wd[e,d,:]  (atomic scatter, <=6 adds/elem)
__global__ __launch_bounds__(256, 4) void k_gemm2(
    const u16* __restrict__ act, const u16* __restrict__ wdb,
    const int* __restrict__ slot_tok, const int* __restrict__ offs,
    const int* __restrict__ counts, float* __restrict__ y) {
  // grid flat = 16(mt) x 16(dt) x 16(e) = 4096 = 8*512
  int b = blockIdx.x;
  int w = (b & 7) * 512 + (b >> 3);
  int mt = w & 15, rest = w >> 4;
  int dt = rest & 15, e = rest >> 4;

  int mcount = counts[e];
  if (mt * 128 >= mcount) return;
  int mrem = mcount - mt * 128; if (mrem > 128) mrem = 128;
  int slotBase = offs[e] + mt * 128;
  int dBase = dt * 128;

  __shared__ u16 sA[128 * 64];
  __shared__ u16 sB[128 * 64];
  __shared__ int tokLds[128];

  int tid = threadIdx.x;
  if (tid < 128) tokLds[tid] = slot_tok[slotBase + (tid < mrem ? tid : 0)];
  __syncthreads();

  int wv = tid >> 6, lane = tid & 63;
  const u16 *aSrc[4], *bSrc[4];
  u16 *aDst[4], *bDst[4];
  const u16* bBase = wdb + ((size_t)e * DMODEL + dBase) * DINTER;
  int r8 = lane >> 3;
  int colOff = ((lane & 7) ^ r8) * 8;   // swizzled 16B-unit
#pragma unroll
  for (int i2 = 0; i2 < 4; ++i2) {
    int chunk = wv * 4 + i2;
    int row = chunk * 8 + r8;
    aSrc[i2] = act + (size_t)(slotBase + row) * DINTER + colOff;  // act padded rows
    bSrc[i2] = bBase + (size_t)row * DINTER + colOff;
    aDst[i2] = sA + chunk * 512;
    bDst[i2] = sB + chunk * 512;
  }

  f32x4 acc[4][4] = {};
  int fr = lane & 15, fq = lane >> 4;
  int wr = (wv >> 1) * 64, wc = (wv & 1) * 64;

  for (int kb = 0; kb < DINTER / 64; ++kb) {
    int kOff = kb * 64;
    __syncthreads();
#pragma unroll
    for (int i2 = 0; i2 < 4; ++i2) {
      gl2lds16(aSrc[i2] + kOff, aDst[i2]);
      gl2lds16(bSrc[i2] + kOff, bDst[i2]);
    }
    __syncthreads();
#pragma unroll
    for (int kf = 0; kf < 2; ++kf) {
      bf16x8 af[4], bb[4];
#pragma unroll
      for (int mf = 0; mf < 4; ++mf) {
        int row = wr + mf * 16 + fr;
        int cu = ((kf * 4 + fq) ^ (row & 7)) * 8;
        af[mf] = *(const bf16x8*)&sA[row * 64 + cu];
      }
#pragma unroll
      for (int nf = 0; nf < 4; ++nf) {
        int row = wc + nf * 16 + fr;
        int cu = ((kf * 4 + fq) ^ (row & 7)) * 8;
        bb[nf] = *(const bf16x8*)&sB[row * 64 + cu];
      }
#pragma unroll
      for (int mf = 0; mf < 4; ++mf)
#pragma unroll
        for (int nf = 0; nf < 4; ++nf)
          acc[mf][nf] = __builtin_amdgcn_mfma_f32_16x16x32_bf16(af[mf], bb[nf], acc[mf][nf], 0, 0, 0);
    }
  }
#pragma unroll
  for (int mf = 0; mf < 4; ++mf)
#pragma unroll
    for (int nf = 0; nf < 4; ++nf)
#pragma unroll
      for (int r = 0; r < 4; ++r) {
        int row = wr + mf * 16 + fq * 4 + r;
        if (row < mrem) {
          int t = tokLds[row];
          atomicAdd(y + (size_t)t * DMODEL + dBase + wc + nf * 16 + fr, acc[mf][nf][r]);
        }
      }
}

extern "C" void kernel_launch(void* const* d_in, const int* in_sizes, int n_in,
                              void* d_out, int out_size, void* d_ws, size_t ws_size,
                              hipStream_t stream) {
  const float* x       = (const float*)d_in[0];
  const float* weights = (const float*)d_in[1];
  const int*   indices = (const int*)d_in[2];
  const float* Wg      = (const float*)d_in[3];
  const float* Wu      = (const float*)d_in[4];
  const float* Wd      = (const float*)d_in[5];
  float* y = (float*)d_out;

  const size_t WELEM = (size_t)NE * DINTER * DMODEL;  // 46.1M elems per weight tensor

  char* ws = (char*)d_ws;
  size_t o = 0;
  float* gate_w = (float*)(ws + o); o += (size_t)TT * NE * 4;
  size_t ctrlOff = o;
  int* counts = (int*)(ws + o);
  int* offs   = (int*)(ws + o + 64);
  int* cursor = (int*)(ws + o + 192);
  o += 256;
  int*   slot_tok  = (int*)(ws + o);   o += (size_t)PMAX * 4;
  float* slot_gate = (float*)(ws + o); o += (size_t)PMAX * 4;
  u16* xb  = (u16*)(ws + o); o += (size_t)TT * DMODEL * 2;
  u16* act = (u16*)(ws + o); o += (size_t)(PMAX + 128) * DINTER * 2; // +128 pad rows
  u16* wgb = (u16*)(ws + o); o += WELEM * 2;
  u16* wub = (u16*)(ws + o); o += WELEM * 2;
  u16* wdb = (u16*)(ws + o); o += WELEM * 2;   // total ~306 MB
  (void)ws_size; (void)in_sizes; (void)n_in;

  hipMemsetAsync(d_out, 0, (size_t)out_size * 4, stream);
  hipMemsetAsync(ws + ctrlOff, 0, 256, stream);

  k_gate<<<TT * NE / 256, 256, 0, stream>>>(weights, indices, gate_w, counts);
  k_scan<<<1, 64, 0, stream>>>(counts, offs);
  k_fill<<<TT * NE / 256, 256, 0, stream>>>(gate_w, offs, cursor, slot_tok, slot_gate);
  k_castall<<<2048, 256, 0, stream>>>(x, xb, Wg, wgb, Wu, wub, Wd, wdb);
  k_gemm1<<<2816, 256, 0, stream>>>(xb, wgb, wub, slot_tok, slot_gate, offs, counts, act);
  k_gemm2<<<4096, 256, 0, stream>>>(act, wdb, slot_tok, offs, counts, y);
}

// Round 16
// 590.423 us; speedup vs baseline: 1.4306x; 1.3675x over previous
//
#include <hip/hip_runtime.h>
#include <hip/hip_bf16.h>
#include <cstdint>

// Problem constants (from reference)
#define TT     2048   // tokens
#define KSEL   6      // experts per token
#define DMODEL 2048   // model dim
#define DINTER 1408   // moe intermediate dim
#define NE     16     // routed experts
#define PMAX   (TT * KSEL)

typedef short bf16x8 __attribute__((ext_vector_type(8)));
typedef float f32x4 __attribute__((ext_vector_type(4)));
typedef unsigned short u16;
typedef u16 u16x8 __attribute__((ext_vector_type(8)));

__device__ __forceinline__ u16 f2bf(float f) {
  union { float f; unsigned u; } v; v.f = f;
  return (u16)((v.u + 0x7FFFu + ((v.u >> 16) & 1u)) >> 16);  // RNE
}

__device__ __forceinline__ void gl2lds16(const void* g, void* l) {
  __builtin_amdgcn_global_load_lds((const __attribute__((address_space(1))) void*)g,
                                   (__attribute__((address_space(3))) void*)l,
                                   16, 0, 0);
}

// gate_w[t,e] = sum_k weights[t,k]*(indices[t,k]==e); count routed (t,e) pairs
__global__ void k_gate(const float* __restrict__ w, const int* __restrict__ idx,
                       float* __restrict__ gate_w, int* __restrict__ counts) {
  int g = blockIdx.x * 256 + threadIdx.x;  // T*E threads
  int t = g >> 4, e = g & 15;
  const int* ip = idx + t * KSEL;
  const float* wp = w + t * KSEL;
  float s = 0.f;
#pragma unroll
  for (int k = 0; k < KSEL; ++k) s += (ip[k] == e) ? wp[k] : 0.f;
  gate_w[g] = s;
  if (s != 0.f) atomicAdd(counts + e, 1);
}

__global__ void k_scan(const int* __restrict__ counts, int* __restrict__ offs) {
  if (threadIdx.x == 0 && blockIdx.x == 0) {
    int r = 0;
#pragma unroll
    for (int e = 0; e < NE; ++e) { offs[e] = r; r += counts[e]; }
    offs[NE] = r;
  }
}

__global__ void k_fill(const float* __restrict__ gate_w, const int* __restrict__ offs,
                       int* __restrict__ cursor, int* __restrict__ slot_tok,
                       float* __restrict__ slot_gate) {
  int g = blockIdx.x * 256 + threadIdx.x;
  int t = g >> 4, e = g & 15;
  float s = gate_w[g];
  if (s != 0.f) {
    int p = atomicAdd(cursor + e, 1);
    int sl = offs[e] + p;
    slot_tok[sl] = t;
    slot_gate[sl] = s;
  }
}

// single merged fp32->bf16 cast over 4 tensors (x, Wg, Wu, Wd), 8 elems/thread
// 855 MB total traffic -> ~136 us at copy BW floor; measured ~4.7 TB/s.
#define XV8   (TT * DMODEL / 8)                      // 524288
#define WV8   (NE * DINTER * DMODEL / 8)             // 5767168
__global__ void k_castall(const float* __restrict__ x,  u16* __restrict__ xb,
                          const float* __restrict__ wg, u16* __restrict__ wgb,
                          const float* __restrict__ wu, u16* __restrict__ wub,
                          const float* __restrict__ wd, u16* __restrict__ wdb) {
  const int total = XV8 + 3 * WV8;
  int stride = gridDim.x * 256;
  for (int i = blockIdx.x * 256 + threadIdx.x; i < total; i += stride) {
    const float* src; u16* dst; int j;
    if (i < XV8)                { src = x;  dst = xb;  j = i; }
    else if (i < XV8 + WV8)     { src = wg; dst = wgb; j = i - XV8; }
    else if (i < XV8 + 2 * WV8) { src = wu; dst = wub; j = i - XV8 - WV8; }
    else                        { src = wd; dst = wdb; j = i - XV8 - 2 * WV8; }
    const float4* p = (const float4*)src + (size_t)j * 2;
    float4 v0 = p[0], v1 = p[1];
    u16x8 o;
    o[0] = f2bf(v0.x); o[1] = f2bf(v0.y); o[2] = f2bf(v0.z); o[3] = f2bf(v0.w);
    o[4] = f2bf(v1.x); o[5] = f2bf(v1.y); o[6] = f2bf(v1.z); o[7] = f2bf(v1.w);
    *(u16x8*)(dst + (size_t)j * 8) = o;
  }
}

// ---------------------------------------------------------------------------
// LDS XOR swizzle (G4 / rule #21): rows are 64 bf16 = 8 16B-units; write side
// pre-permutes the GLOBAL source unit (u' = u ^ (row&7), LDS dest linear per
// gl2lds HW rule), read side applies the same XOR -> bank-conflict-free
// (R6 measured: SQ_LDS_BANK_CONFLICT = 0).
//
// Register budget (m69 ladder, unified VGPR/AGPR): this tile = 128 AGPR acc
// + ~108 VGPR = ~236/wave -> exactly 2 waves/SIMD. (256,3) forces spill
// (R15: WRITE +35 MB, 2x slower). Keep (256,2) for gemm1.
// ---------------------------------------------------------------------------

// GEMM1: act[slot, i] = silu(x@WgT)*(x@WuT)*gate, per expert token-group.
__global__ __launch_bounds__(256, 2) void k_gemm1(
    const u16* __restrict__ xb, const u16* __restrict__ wgb, const u16* __restrict__ wub,
    const int* __restrict__ slot_tok, const float* __restrict__ slot_gate,
    const int* __restrict__ offs, const int* __restrict__ counts,
    u16* __restrict__ act) {
  // XCD-chunked swizzle: grid flat = 16(mt) x 11(it) x 16(e) = 2816 = 8*352
  int b = blockIdx.x;
  int w = (b & 7) * 352 + (b >> 3);
  int mt = w & 15, rest = w >> 4;
  int it = rest % 11, e = rest / 11;

  int mcount = counts[e];
  if (mt * 128 >= mcount) return;
  int mrem = mcount - mt * 128; if (mrem > 128) mrem = 128;
  int slotBase = offs[e] + mt * 128;
  int iBase = it * 128;

  __shared__ u16 sA[128 * 64];
  __shared__ u16 sG[128 * 64];
  __shared__ u16 sU[128 * 64];
  __shared__ int tokLds[128];
  __shared__ float gateLds[128];

  int tid = threadIdx.x;
  if (tid < 128) {
    int rl = tid < mrem ? tid : 0;        // pad rows clamp to row 0 (valid addr)
    tokLds[tid] = slot_tok[slotBase + rl];
    gateLds[tid] = (tid < mrem) ? slot_gate[slotBase + rl] : 0.f;
  }
  __syncthreads();

  int wv = tid >> 6, lane = tid & 63;
  // staging: 16 chunks of 1KB (8 rows x 128B); linear LDS dest, swizzled source
  const u16 *aSrc[4], *gSrc[4], *uSrc[4];
  u16 *aDst[4], *gDst[4], *uDst[4];
  const u16* gBase = wgb + ((size_t)e * DINTER + iBase) * DMODEL;
  const u16* uBase = wub + ((size_t)e * DINTER + iBase) * DMODEL;
  int r8 = lane >> 3;
  int colOff = ((lane & 7) ^ r8) * 8;   // swizzled 16B-unit within the row
#pragma unroll
  for (int i2 = 0; i2 < 4; ++i2) {
    int chunk = wv * 4 + i2;
    int row = chunk * 8 + r8;
    aSrc[i2] = xb + (size_t)tokLds[row] * DMODEL + colOff;
    gSrc[i2] = gBase + (size_t)row * DMODEL + colOff;
    uSrc[i2] = uBase + (size_t)row * DMODEL + colOff;
    aDst[i2] = sA + chunk * 512;
    gDst[i2] = sG + chunk * 512;
    uDst[i2] = sU + chunk * 512;
  }

  f32x4 accg[4][4] = {};
  f32x4 accu[4][4] = {};
  int fr = lane & 15, fq = lane >> 4;
  int wr = (wv >> 1) * 64, wc = (wv & 1) * 64;

  for (int kb = 0; kb < DMODEL / 64; ++kb) {
    int kOff = kb * 64;
    __syncthreads();
#pragma unroll
    for (int i2 = 0; i2 < 4; ++i2) {
      gl2lds16(aSrc[i2] + kOff, aDst[i2]);
      gl2lds16(gSrc[i2] + kOff, gDst[i2]);
      gl2lds16(uSrc[i2] + kOff, uDst[i2]);
    }
    __syncthreads();
#pragma unroll
    for (int kf = 0; kf < 2; ++kf) {
      bf16x8 af[4], bg[4], bu[4];
#pragma unroll
      for (int mf = 0; mf < 4; ++mf) {
        int row = wr + mf * 16 + fr;
        int cu = ((kf * 4 + fq) ^ (row & 7)) * 8;
        af[mf] = *(const bf16x8*)&sA[row * 64 + cu];
      }
#pragma unroll
      for (int nf = 0; nf < 4; ++nf) {
        int row = wc + nf * 16 + fr;
        int cu = ((kf * 4 + fq) ^ (row & 7)) * 8;
        bg[nf] = *(const bf16x8*)&sG[row * 64 + cu];
        bu[nf] = *(const bf16x8*)&sU[row * 64 + cu];
      }
#pragma unroll
      for (int mf = 0; mf < 4; ++mf)
#pragma unroll
        for (int nf = 0; nf < 4; ++nf) {
          accg[mf][nf] = __builtin_amdgcn_mfma_f32_16x16x32_bf16(af[mf], bg[nf], accg[mf][nf], 0, 0, 0);
          accu[mf][nf] = __builtin_amdgcn_mfma_f32_16x16x32_bf16(af[mf], bu[nf], accu[mf][nf], 0, 0, 0);
        }
    }
  }
  // epilogue: act = silu(g)*u*gate -> bf16  (D layout: col=lane&15, row=(lane>>4)*4+r)
#pragma unroll
  for (int mf = 0; mf < 4; ++mf)
#pragma unroll
    for (int nf = 0; nf < 4; ++nf)
#pragma unroll
      for (int r = 0; r < 4; ++r) {
        int row = wr + mf * 16 + fq * 4 + r;
        if (row < mrem) {
          float g = accg[mf][nf][r], u = accu[mf][nf][r];
          float a = g / (1.f + __expf(-g)) * u * gateLds[row];
          act[(size_t)(slotBase + row) * DINTER + iBase + wc + nf * 16 + fr] = f2bf(a);
        }
      }
}

// GEMM2: y[tok, d] += act[slot,:] @ Wd[e,d,:]  (atomic scatter, <=6 adds/elem)
// (256,3): 170-reg/wave budget fits 64 AGPR acc + ~95 VGPR without spill;
// the old (256,4) capped at ~128/wave -> chronic mild spill (403 TF vs 650).
__global__ __launch_bounds__(256, 3) void k_gemm2(
    const u16* __restrict__ act, const u16* __restrict__ wdb,
    const int* __restrict__ slot_tok, const int* __restrict__ offs,
    const int* __restrict__ counts, float* __restrict__ y) {
  // grid flat = 16(mt) x 16(dt) x 16(e) = 4096 = 8*512
  int b = blockIdx.x;
  int w = (b & 7) * 512 + (b >> 3);
  int mt = w & 15, rest = w >> 4;
  int dt = rest & 15, e = rest >> 4;

  int mcount = counts[e];
  if (mt * 128 >= mcount) return;
  int mrem = mcount - mt * 128; if (mrem > 128) mrem = 128;
  int slotBase = offs[e] + mt * 128;
  int dBase = dt * 128;

  __shared__ u16 sA[128 * 64];
  __shared__ u16 sB[128 * 64];
  __shared__ int tokLds[128];

  int tid = threadIdx.x;
  if (tid < 128) tokLds[tid] = slot_tok[slotBase + (tid < mrem ? tid : 0)];
  __syncthreads();

  int wv = tid >> 6, lane = tid & 63;
  const u16 *aSrc[4], *bSrc[4];
  u16 *aDst[4], *bDst[4];
  const u16* bBase = wdb + ((size_t)e * DMODEL + dBase) * DINTER;
  int r8 = lane >> 3;
  int colOff = ((lane & 7) ^ r8) * 8;   // swizzled 16B-unit
#pragma unroll
  for (int i2 = 0; i2 < 4; ++i2) {
    int chunk = wv * 4 + i2;
    int row = chunk * 8 + r8;
    aSrc[i2] = act + (size_t)(slotBase + row) * DINTER + colOff;  // act padded rows
    bSrc[i2] = bBase + (size_t)row * DINTER + colOff;
    aDst[i2] = sA + chunk * 512;
    bDst[i2] = sB + chunk * 512;
  }

  f32x4 acc[4][4] = {};
  int fr = lane & 15, fq = lane >> 4;
  int wr = (wv >> 1) * 64, wc = (wv & 1) * 64;

  for (int kb = 0; kb < DINTER / 64; ++kb) {
    int kOff = kb * 64;
    __syncthreads();
#pragma unroll
    for (int i2 = 0; i2 < 4; ++i2) {
      gl2lds16(aSrc[i2] + kOff, aDst[i2]);
      gl2lds16(bSrc[i2] + kOff, bDst[i2]);
    }
    __syncthreads();
#pragma unroll
    for (int kf = 0; kf < 2; ++kf) {
      bf16x8 af[4], bb[4];
#pragma unroll
      for (int mf = 0; mf < 4; ++mf) {
        int row = wr + mf * 16 + fr;
        int cu = ((kf * 4 + fq) ^ (row & 7)) * 8;
        af[mf] = *(const bf16x8*)&sA[row * 64 + cu];
      }
#pragma unroll
      for (int nf = 0; nf < 4; ++nf) {
        int row = wc + nf * 16 + fr;
        int cu = ((kf * 4 + fq) ^ (row & 7)) * 8;
        bb[nf] = *(const bf16x8*)&sB[row * 64 + cu];
      }
#pragma unroll
      for (int mf = 0; mf < 4; ++mf)
#pragma unroll
        for (int nf = 0; nf < 4; ++nf)
          acc[mf][nf] = __builtin_amdgcn_mfma_f32_16x16x32_bf16(af[mf], bb[nf], acc[mf][nf], 0, 0, 0);
    }
  }
#pragma unroll
  for (int mf = 0; mf < 4; ++mf)
#pragma unroll
    for (int nf = 0; nf < 4; ++nf)
#pragma unroll
      for (int r = 0; r < 4; ++r) {
        int row = wr + mf * 16 + fq * 4 + r;
        if (row < mrem) {
          int t = tokLds[row];
          atomicAdd(y + (size_t)t * DMODEL + dBase + wc + nf * 16 + fr, acc[mf][nf][r]);
        }
      }
}

extern "C" void kernel_launch(void* const* d_in, const int* in_sizes, int n_in,
                              void* d_out, int out_size, void* d_ws, size_t ws_size,
                              hipStream_t stream) {
  const float* x       = (const float*)d_in[0];
  const float* weights = (const float*)d_in[1];
  const int*   indices = (const int*)d_in[2];
  const float* Wg      = (const float*)d_in[3];
  const float* Wu      = (const float*)d_in[4];
  const float* Wd      = (const float*)d_in[5];
  float* y = (float*)d_out;

  const size_t WELEM = (size_t)NE * DINTER * DMODEL;  // 46.1M elems per weight tensor

  char* ws = (char*)d_ws;
  size_t o = 0;
  float* gate_w = (float*)(ws + o); o += (size_t)TT * NE * 4;
  size_t ctrlOff = o;
  int* counts = (int*)(ws + o);
  int* offs   = (int*)(ws + o + 64);
  int* cursor = (int*)(ws + o + 192);
  o += 256;
  int*   slot_tok  = (int*)(ws + o);   o += (size_t)PMAX * 4;
  float* slot_gate = (float*)(ws + o); o += (size_t)PMAX * 4;
  u16* xb  = (u16*)(ws + o); o += (size_t)TT * DMODEL * 2;
  u16* act = (u16*)(ws + o); o += (size_t)(PMAX + 128) * DINTER * 2; // +128 pad rows
  u16* wgb = (u16*)(ws + o); o += WELEM * 2;
  u16* wub = (u16*)(ws + o); o += WELEM * 2;
  u16* wdb = (u16*)(ws + o); o += WELEM * 2;   // total ~306 MB
  (void)ws_size; (void)in_sizes; (void)n_in;

  hipMemsetAsync(d_out, 0, (size_t)out_size * 4, stream);
  hipMemsetAsync(ws + ctrlOff, 0, 256, stream);

  k_gate<<<TT * NE / 256, 256, 0, stream>>>(weights, indices, gate_w, counts);
  k_scan<<<1, 64, 0, stream>>>(counts, offs);
  k_fill<<<TT * NE / 256, 256, 0, stream>>>(gate_w, offs, cursor, slot_tok, slot_gate);
  k_castall<<<2048, 256, 0, stream>>>(x, xb, Wg, wgb, Wu, wub, Wd, wdb);
  k_gemm1<<<2816, 256, 0, stream>>>(xb, wgb, wub, slot_tok, slot_gate, offs, counts, act);
  k_gemm2<<<4096, 256, 0, stream>>>(act, wdb, slot_tok, offs, counts, y);
}